// Round 5
// baseline (257.271 us; speedup 1.0000x reference)
//
#include <hip/hip_runtime.h>
#include <hip/hip_bf16.h>

// Problem: B=8, C=256, H=W=64 -> N=4096, inter=32. fp32 in/out.
#define BB 8
#define CC 256
#define NN 4096
#define II 32

typedef __bf16 bf16_t;
typedef bf16_t bf16x8 __attribute__((ext_vector_type(8)));
typedef float f32x4 __attribute__((ext_vector_type(4)));

// ---------------------------------------------------------------------------
// Weight pre-convert: Wb[320][256] bf16 = [Wq(32); Wk(32); Wv(256)] rows.
// ---------------------------------------------------------------------------
__global__ __launch_bounds__(256) void wconv(
    const float* __restrict__ Wq, const float* __restrict__ Wk,
    const float* __restrict__ Wv, bf16_t* __restrict__ Wb) {
  int idx = blockIdx.x * 256 + threadIdx.x;  // < 320*256
  int o = idx >> 8, c = idx & 255;
  float w = (o < 32) ? Wq[o * 256 + c]
          : (o < 64) ? Wk[(o - 32) * 256 + c]
                     : Wv[(o - 64) * 256 + c];
  Wb[idx] = (bf16_t)w;
}

// ---------------------------------------------------------------------------
// x transpose+convert: xt[b][n][c] bf16 from x[b][c][n] fp32.
// 64c x 64n tiles through LDS; coalesced float4 reads, uint2 writes.
// ---------------------------------------------------------------------------
__global__ __launch_bounds__(256) void xcvt(
    const float* __restrict__ x, bf16_t* __restrict__ xt) {
  __shared__ bf16_t tl[64][72];  // [n][c], padded
  const int t  = threadIdx.x;
  const int n0 = blockIdx.x * 64, c0 = blockIdx.y * 64, b = blockIdx.z;

  const float* xb = x + ((size_t)b * CC + c0) * NN + n0;
#pragma unroll
  for (int p = 0; p < 4; ++p) {
    int cl = (t >> 4) + 16 * p;
    int nl = (t & 15) * 4;
    float4 v = *(const float4*)&xb[(size_t)cl * NN + nl];
    tl[nl + 0][cl] = (bf16_t)v.x;
    tl[nl + 1][cl] = (bf16_t)v.y;
    tl[nl + 2][cl] = (bf16_t)v.z;
    tl[nl + 3][cl] = (bf16_t)v.w;
  }
  __syncthreads();
  bf16_t* xtb = xt + ((size_t)b * NN + n0) * CC + c0;
#pragma unroll
  for (int p = 0; p < 4; ++p) {
    int nl = (t >> 4) + 16 * p;
    int cl = (t & 15) * 4;
    union { bf16_t h[4]; uint2 u; } pk;
    pk.h[0] = tl[nl][cl + 0]; pk.h[1] = tl[nl][cl + 1];
    pk.h[2] = tl[nl][cl + 2]; pk.h[3] = tl[nl][cl + 3];
    *(uint2*)&xtb[(size_t)nl * CC + cl] = pk.u;
  }
}

// ---------------------------------------------------------------------------
// Fused q/k/v projection as MFMA GEMM, no LDS, all-b128 loads.
//   out[o, n] = sum_c W[o,c] * xt[b,n,c]   (o in 320 = 20 o-tiles of 16)
// XCD swizzle: 1-D grid 1024; bid%8 = XCD. The 4 og-copies of one
// (b, n-slice) share an XCD -> xt slice is fetched from HBM once, then
// L2-hit. Per-XCD set: 32 slices x 64KB = 2MB xt + 160KB Wb < 4MB L2.
// ---------------------------------------------------------------------------
__global__ __launch_bounds__(256, 4) void qkv_proj(
    const bf16_t* __restrict__ xt, const bf16_t* __restrict__ Wb,
    const float* __restrict__ bq, const float* __restrict__ bk,
    const float* __restrict__ bv,
    bf16_t* __restrict__ q, bf16_t* __restrict__ k, bf16_t* __restrict__ v) {
  const int t  = threadIdx.x;
  const int w  = t >> 6;
  const int l  = t & 63;
  const int lo = l & 15;
  const int q4 = l >> 4;
  // Swizzled decode: bid = xcd + 8*(og + 4*s); gs = s*8 + xcd -> (b, bx)
  const int bid = blockIdx.x;
  const int xcd = bid & 7;
  const int j   = bid >> 3;
  const int og  = j & 3;          // o-tile group: tiles [og*5, og*5+5)
  const int gs  = (j >> 2) * 8 + xcd;
  const int bx  = gs & 31;
  const int b   = gs >> 5;
  const int nbase = bx * 128 + w * 32;

  const bf16_t* xb = xt + (size_t)b * NN * CC;

  f32x4 acc[5][2];  // [o-tile][n-subtile]
#pragma unroll
  for (int ot = 0; ot < 5; ++ot)
#pragma unroll
    for (int ms = 0; ms < 2; ++ms) acc[ot][ms] = (f32x4){0.f, 0.f, 0.f, 0.f};

#pragma unroll 2
  for (int ks = 0; ks < 8; ++ks) {
    const int c0 = ks * 32 + q4 * 8;
    bf16x8 af[2];
#pragma unroll
    for (int ms = 0; ms < 2; ++ms)
      af[ms] = *(const bf16x8*)&xb[(size_t)(nbase + ms * 16 + lo) * CC + c0];
    bf16x8 bw[5];
#pragma unroll
    for (int ot = 0; ot < 5; ++ot)
      bw[ot] = *(const bf16x8*)&Wb[((og * 5 + ot) * 16 + lo) * 256 + c0];
#pragma unroll
    for (int ms = 0; ms < 2; ++ms)
#pragma unroll
      for (int ot = 0; ot < 5; ++ot)
        acc[ot][ms] = __builtin_amdgcn_mfma_f32_16x16x32_bf16(
            af[ms], bw[ot], acc[ot][ms], 0, 0, 0);
  }

  // Epilogue: q,k -> [b][n][32] bf16 (2B scatter); v -> [b][c][n] bf16.
#pragma unroll
  for (int ot = 0; ot < 5; ++ot) {
    const int gt = og * 5 + ot;  // global o-tile
    if (gt < 4) {
      const bool isq = gt < 2;
      const int i = (gt & 1) * 16 + lo;
      const float bias = isq ? bq[i] : bk[i];
      bf16_t* dst = (isq ? q : k) + (size_t)b * NN * II;
#pragma unroll
      for (int ms = 0; ms < 2; ++ms) {
#pragma unroll
        for (int r = 0; r < 4; ++r) {
          int n = nbase + ms * 16 + q4 * 4 + r;
          dst[(size_t)n * II + i] = (bf16_t)(acc[ot][ms][r] + bias);
        }
      }
    } else {
      const int cv = (gt - 4) * 16 + lo;
      const float bias = bv[cv];
      bf16_t* dst = v + ((size_t)b * CC + cv) * NN;
#pragma unroll
      for (int ms = 0; ms < 2; ++ms) {
        union { bf16_t h[4]; uint2 u; } pk;
#pragma unroll
        for (int r = 0; r < 4; ++r) pk.h[r] = (bf16_t)(acc[ot][ms][r] + bias);
        *(uint2*)&dst[nbase + ms * 16 + q4 * 4] = pk.u;
      }
    }
  }
}

// ---------------------------------------------------------------------------
// MFMA attention, pipelined + XCD-pinned. 1-D grid 512: bid%8 = batch = XCD
// -> per-XCD L2 set = v(2MB)+k(256KB)+q(256KB) ~ 2.5MB < 4MB: K/V frag
// loads become L2 hits, hidden behind phase 1 + barrier.
//   Top of iter: issue 8 V-frag b128 loads + next-iter K-frag load.
//   Phase 1: S_T = K.Q^T (4 mfma), exp -> bf16 P to LDS (dbuf, swizzled).
//   ONE __syncthreads per iter. Phase 2: O += V.P^T (32 mfma).
// No max-subtraction: |s|<~35, exp fits fp32/bf16 range; partials add.
// ---------------------------------------------------------------------------
__global__ __launch_bounds__(256, 2) void attn_mfma(
    const bf16_t* __restrict__ q, const bf16_t* __restrict__ k,
    const bf16_t* __restrict__ v, const float* __restrict__ x,
    const float* __restrict__ gamma, float* __restrict__ out) {
  __shared__ bf16_t Pld[2][64 * 64];  // 16 KB double-buffered P
  __shared__ float lred[16][64];
  __shared__ float lfin[64];

  const int t  = threadIdx.x;
  const int w  = t >> 6;   // wave id = c-split
  const int l  = t & 63;
  const int lo = l & 15;
  const int q4 = l >> 4;
  const int b  = blockIdx.x & 7;            // batch = XCD
  const int m0 = (blockIdx.x >> 3) * 64;

  const bf16_t* qb = q + (size_t)b * NN * II;
  const bf16_t* kb = k + (size_t)b * NN * II;
  const bf16_t* vb = v + (size_t)b * CC * NN;

  // Q B-frags, loop-invariant, in registers
  bf16x8 qf[4];
#pragma unroll
  for (int mt = 0; mt < 4; ++mt)
    qf[mt] = *(const bf16x8*)(qb + (size_t)(m0 + mt * 16 + lo) * II + q4 * 8);

  f32x4 acc[4][4];  // [ct][mt]
#pragma unroll
  for (int ct = 0; ct < 4; ++ct)
#pragma unroll
    for (int mt = 0; mt < 4; ++mt) acc[ct][mt] = (f32x4){0.f, 0.f, 0.f, 0.f};
  float lp[4] = {0.f, 0.f, 0.f, 0.f};

  const int cbase = w * 64;
  const f32x4 zero = (f32x4){0.f, 0.f, 0.f, 0.f};

  // Prime K frag for n1 = 0
  bf16x8 kf = *(const bf16x8*)(kb + (size_t)(w * 16 + lo) * II + q4 * 8);

  for (int n1 = 0, it = 0; n1 < NN; n1 += 64, ++it) {
    // ---- issue V frags for THIS iter + K frag for NEXT iter up front ----
    bf16x8 vf[8];
#pragma unroll
    for (int kc = 0; kc < 2; ++kc)
#pragma unroll
      for (int ct = 0; ct < 4; ++ct)
        vf[kc * 4 + ct] = *(const bf16x8*)(vb +
            (size_t)(cbase + ct * 16 + lo) * NN + n1 + kc * 32 + q4 * 8);
    const int n_next = (n1 + 64) & (NN - 1);  // wraps to 0 on last iter (discarded)
    bf16x8 kf_next = *(const bf16x8*)(kb + (size_t)(n_next + w * 16 + lo) * II + q4 * 8);

    // ---- Phase 1: scores for n-sub w ----
    bf16_t* Pb = Pld[it & 1];
#pragma unroll
    for (int mt = 0; mt < 4; ++mt) {
      f32x4 s = __builtin_amdgcn_mfma_f32_16x16x32_bf16(kf, qf[mt], zero, 0, 0, 0);
      float e0 = __expf(s[0]), e1 = __expf(s[1]), e2 = __expf(s[2]), e3 = __expf(s[3]);
      lp[mt] += (e0 + e1) + (e2 + e3);
      union { bf16_t h[4]; uint2 u2; } ph;
      ph.h[0] = (bf16_t)e0; ph.h[1] = (bf16_t)e1;
      ph.h[2] = (bf16_t)e2; ph.h[3] = (bf16_t)e3;
      // P[m][n_local], n_local = w*16 + q4*4 + r. 16B chunk c8 at row m
      // lives at phys chunk c8 ^ (m&7). Write = 8B half-chunk.
      int m_loc = mt * 16 + lo;
      int c8    = w * 2 + (q4 >> 1);
      int elem  = m_loc * 64 + ((c8 ^ (m_loc & 7)) * 8) + (q4 & 1) * 4;
      *(uint2*)&Pb[elem] = ph.u2;
    }
    __syncthreads();

    // ---- Phase 2: PV ----
#pragma unroll
    for (int kc = 0; kc < 2; ++kc) {
      bf16x8 pf[4];
#pragma unroll
      for (int mt = 0; mt < 4; ++mt) {
        int m_loc = mt * 16 + lo;
        int c8    = kc * 4 + q4;
        pf[mt] = *(const bf16x8*)&Pb[m_loc * 64 + ((c8 ^ (m_loc & 7)) * 8)];
      }
#pragma unroll
      for (int ct = 0; ct < 4; ++ct)
#pragma unroll
        for (int mt = 0; mt < 4; ++mt)
          acc[ct][mt] = __builtin_amdgcn_mfma_f32_16x16x32_bf16(
              vf[kc * 4 + ct], pf[mt], acc[ct][mt], 0, 0, 0);
    }
    kf = kf_next;
  }

  // ---- softmax denominator reduction ----
#pragma unroll
  for (int mt = 0; mt < 4; ++mt) lred[w * 4 + q4][mt * 16 + lo] = lp[mt];
  __syncthreads();
  if (t < 64) {
    float s = 0.f;
#pragma unroll
    for (int j = 0; j < 16; ++j) s += lred[j][t];
    lfin[t] = s;
  }
  __syncthreads();

  const float g = gamma[0];
  float linv[4];
#pragma unroll
  for (int mt = 0; mt < 4; ++mt) linv[mt] = 1.0f / lfin[mt * 16 + lo];

  // ---- epilogue: out = gamma * O/l + x ----
#pragma unroll
  for (int ct = 0; ct < 4; ++ct) {
#pragma unroll
    for (int r = 0; r < 4; ++r) {
      int c = cbase + ct * 16 + q4 * 4 + r;
      const float* xrow = x + ((size_t)b * CC + c) * NN + m0;
      float* orow       = out + ((size_t)b * CC + c) * NN + m0;
#pragma unroll
      for (int mt = 0; mt < 4; ++mt) {
        int m = mt * 16 + lo;
        orow[m] = g * acc[ct][mt][r] * linv[mt] + xrow[m];
      }
    }
  }
}

// ---------------------------------------------------------------------------
extern "C" void kernel_launch(void* const* d_in, const int* in_sizes, int n_in,
                              void* d_out, int out_size, void* d_ws, size_t ws_size,
                              hipStream_t stream) {
  const float* x     = (const float*)d_in[0];
  const float* Wq    = (const float*)d_in[1];
  const float* bq    = (const float*)d_in[2];
  const float* Wk    = (const float*)d_in[3];
  const float* bk    = (const float*)d_in[4];
  const float* Wv    = (const float*)d_in[5];
  const float* bv    = (const float*)d_in[6];
  const float* gamma = (const float*)d_in[7];
  float* out = (float*)d_out;

  // Workspace (bf16): q 2MB, k 2MB, v 16MB, Wb 160KB, xt 16MB (~36.2MB)
  bf16_t* ws = (bf16_t*)d_ws;
  bf16_t* q  = ws;
  bf16_t* k  = q + (size_t)BB * NN * II;
  bf16_t* v  = k + (size_t)BB * NN * II;
  bf16_t* Wb = v + (size_t)BB * CC * NN;
  bf16_t* xt = Wb + (size_t)320 * 256;

  wconv<<<dim3(320), 256, 0, stream>>>(Wq, Wk, Wv, Wb);

  dim3 gx(NN / 64, CC / 64, BB);
  xcvt<<<gx, 256, 0, stream>>>(x, xt);

  qkv_proj<<<dim3(1024), 256, 0, stream>>>(xt, Wb, bq, bk, bv, q, k, v);

  attn_mfma<<<dim3(512), 256, 0, stream>>>(q, k, v, x, gamma, out);
}